// Round 5
// baseline (2501.784 us; speedup 1.0000x reference)
//
#include <hip/hip_runtime.h>

// LIF layer: Wx = x @ W^T (f64), then scan over T. B=64,T=1000,I=1024,H=1024.
// R12: resubmit of R11 (infra-failed twice, never ran on-device).
//     R10 passed (probe found the real f64-MFMA lane map; flag in 1..7),
//     gemm 2255us = 77% of f64 matrix peak, MfmaUtil 85. Residuals:
//     (a) SQ_LDS_BANK_CONFLICT 3.28e7 — bank math shows it is ENTIRELY the
//         Bs writes (16 banks x 8 words = 2x over minimum); A reads/writes
//         are at the 4-words/bank wave64 minimum (conflict-free).
//     (b) Occupancy 34.6% = 3 blocks/CU (50KB LDS).
//     Fix: drop Bs entirely. B fragments are coalesced direct reads from
//     WdT (8MB, L2-resident) into a one-round register double-buffer
//     (+32 VGPR). Kills the conflicted pattern, removes 12 LDS ops per
//     lane-round, LDS 50->33KB -> 4 blocks/CU = 16 waves/CU.
//     Probe + data-driven mapping + R7 vector fallback unchanged.

#define TM 128
#define TN 64
#define MTK 16    // MFMA kernel k-tile
#define VTK 8     // vector-fallback kernel k-tile (R7)
#define LDA 130   // As row stride (doubles); 130*8=1040 B

typedef double v4d __attribute__((ext_vector_type(4)));

// ---- pass 0: WdT[k][n] = (double)W[n][k] ----
__global__ __launch_bounds__(256) void transpose_w(
    const float* __restrict__ W, double* __restrict__ WdT)
{
    __shared__ float t[32][33];
    const int k0 = blockIdx.x * 32;
    const int n0 = blockIdx.y * 32;
    const int tx = threadIdx.x & 31;
    const int ty = threadIdx.x >> 5;   // 0..7
    #pragma unroll
    for (int i = 0; i < 4; i++)
        t[ty + 8 * i][tx] = W[(size_t)(n0 + ty + 8 * i) * 1024 + k0 + tx];
    __syncthreads();
    #pragma unroll
    for (int i = 0; i < 4; i++)
        WdT[(size_t)(k0 + ty + 8 * i) * 1024 + n0 + tx] = (double)t[tx][ty + 8 * i];
}

// ---- probe: discover v_mfma_f64_16x16x4f64 lane mappings on-device ----
// flag = imap*4 + dmap (imap 0/1, dmap 0..3), or 255 = none matched.
//   imap0: A[row=l&15][k=l>>4],  B[k=l>>4][col=l&15]
//   imap1: A[row=l>>2][k=l&3],   B[k=l&3][col=l>>2]
//   dmap0: d[q]=D[4*(l>>4)+q][l&15]     dmap1: d[q]=D[l&15][4*(l>>4)+q]
//   dmap2: d[q]=D[(l>>4)+4*q][l&15]     dmap3: d[q]=D[l&15][(l>>4)+4*q]
// Exact-integer asymmetric matrices -> bit-exact, transpose-detecting.
__global__ __launch_bounds__(64) void probe_mfma_layout(unsigned int* __restrict__ flag)
{
    __shared__ double Am[16][4];
    __shared__ double Bm[4][16];
    const int l = threadIdx.x;
    Am[l & 15][l >> 4] = (double)(1 + (l & 15) + 16 * (l >> 4));          // A[i][k]=1+i+16k
    Bm[l >> 4][l & 15] = 1.0 + 0.5 * (double)((l >> 4) + 4 * (l & 15));   // B[k][j]=1+.5(k+4j)
    __syncthreads();
    const v4d z = {0.0, 0.0, 0.0, 0.0};
    const double a0 = Am[l & 15][l >> 4];
    const double b0 = Bm[l >> 4][l & 15];
    const double a1 = Am[l >> 2][l & 3];
    const double b1 = Bm[l & 3][l >> 2];
    const v4d d0 = __builtin_amdgcn_mfma_f64_16x16x4f64(a0, b0, z, 0, 0, 0);
    const v4d d1 = __builtin_amdgcn_mfma_f64_16x16x4f64(a1, b1, z, 0, 0, 0);
    int ok[8];
    #pragma unroll
    for (int c = 0; c < 8; c++) ok[c] = 1;
    #pragma unroll
    for (int q = 0; q < 4; q++) {
        const int iD[4] = {4 * (l >> 4) + q, l & 15, (l >> 4) + 4 * q, l & 15};
        const int jD[4] = {l & 15, 4 * (l >> 4) + q, l & 15, (l >> 4) + 4 * q};
        #pragma unroll
        for (int dm = 0; dm < 4; dm++) {
            double ref = 0.0;
            #pragma unroll
            for (int k = 0; k < 4; k++) ref += Am[iD[dm]][k] * Bm[k][jD[dm]];
            if (d0[q] != ref) ok[dm] = 0;
            if (d1[q] != ref) ok[4 + dm] = 0;
        }
    }
    unsigned int f = 255u;
    for (int c = 7; c >= 0; --c)
        if (__all(ok[c])) f = (unsigned int)c;   // lowest passing wins
    if (l == 0) *flag = f;
}

// ---- GEMM (MFMA path): C[M,N] = A[M,K](f32) * WdT[K,N](f64) ----
// Runs only for flag in {1..7}. A staged via LDS (conflict-free pattern);
// B read straight from WdT into a register double-buffer (L2-resident).
__global__ __launch_bounds__(256, 4) void gemm_f64_mfma(
    const float* __restrict__ A,
    const double* __restrict__ WdT,
    double* __restrict__ C, int M, int N, int K,
    const unsigned int* __restrict__ flag)
{
    const unsigned int f = *flag;
    if (f - 1u > 6u) return;            // only validated alternatives 1..7

    __shared__ double As[2][MTK][LDA];  // 33,280 B

    const int tid  = threadIdx.x;
    const int lane = tid & 63;
    const int l16  = lane & 15;
    const int kq4  = lane >> 4;
    const int wid  = tid >> 6;          // wave 0..3
    const int wr   = wid >> 1;          // wave row 0/1 (64 rows each)
    const int wc   = wid & 1;           // wave col 0/1 (32 cols each)

    const int imap = (int)(f >> 2);
    const int dmap = (int)(f & 3u);
    const int rowl = imap ? (lane >> 2) : l16;   // A-row / B-col within 16
    const int kl   = imap ? (lane & 3)  : kq4;   // k within the K=4 step
    int rloc, rstep, cloc, cstep;
    switch (dmap) {
        case 0:  rloc = 4 * kq4; rstep = 1; cloc = l16;     cstep = 0; break;
        case 1:  rloc = l16;     rstep = 0; cloc = 4 * kq4; cstep = 1; break;
        case 2:  rloc = kq4;     rstep = 4; cloc = l16;     cstep = 0; break;
        default: rloc = l16;     rstep = 0; cloc = kq4;     cstep = 4; break;
    }

    const int nb0 = blockIdx.x * TN;
    const int tm  = blockIdx.y * TM;

    // A staging roles
    const int rA  = tid >> 1;           // A row 0..127
    const int kA  = (tid & 1) * 4;      // A k-quad base (0 or 4; +8 for 2nd)

    v4d acc[4][2];
    #pragma unroll
    for (int i = 0; i < 4; i++)
        #pragma unroll
        for (int j = 0; j < 2; j++)
            acc[i][j] = (v4d)0.0;

    const int ar = min(tm + rA, M - 1);   // tail guard (loads only)
    const float* Apg = A + (size_t)ar * K;
    // per-lane B base: column nb0+nw+rowl, advancing in k
    const int nw = wc * 32;
    const int mw = wr * 64;
    const double* Bln = WdT + (size_t)kl * N + nb0 + nw + rowl;

    struct AReg { float4 a0, a1; };
    auto issueA = [&](int s) {
        AReg t;
        const int k0 = s * MTK;
        t.a0 = *(const float4*)(Apg + k0 + kA);
        t.a1 = *(const float4*)(Apg + k0 + kA + 8);
        return t;
    };
    auto commitA = [&](int buf, const AReg& t) {
        As[buf][kA + 0][rA] = (double)t.a0.x;
        As[buf][kA + 1][rA] = (double)t.a0.y;
        As[buf][kA + 2][rA] = (double)t.a0.z;
        As[buf][kA + 3][rA] = (double)t.a0.w;
        As[buf][kA + 8][rA] = (double)t.a1.x;
        As[buf][kA + 9][rA] = (double)t.a1.y;
        As[buf][kA + 10][rA] = (double)t.a1.z;
        As[buf][kA + 11][rA] = (double)t.a1.w;
    };

    struct BReg { double b[4][2]; };   // [ks][j], fully unrolled -> registers
    auto loadB = [&](int s) {
        BReg r;
        const int k0 = s * MTK;
        #pragma unroll
        for (int ks = 0; ks < 4; ++ks) {
            const double* bp = Bln + (size_t)(k0 + ks * 4) * N;
            r.b[ks][0] = bp[0];
            r.b[ks][1] = bp[16];
        }
        return r;
    };

    auto compute_tile = [&](int p, const BReg& br) {
        #pragma unroll
        for (int ks = 0; ks < 4; ++ks) {
            const int kk = ks * 4 + kl;
            double av[4];
            #pragma unroll
            for (int i = 0; i < 4; i++) av[i] = As[p][kk][mw + i * 16 + rowl];
            #pragma unroll
            for (int i = 0; i < 4; i++)
                #pragma unroll
                for (int j = 0; j < 2; j++)
                    acc[i][j] = __builtin_amdgcn_mfma_f64_16x16x4f64(
                        av[i], br.b[ks][j], acc[i][j], 0, 0, 0);
        }
    };

    // prologue: stage round 0 into buf 0, B(0) into regs
    BReg bcur = loadB(0);
    commitA(0, issueA(0));
    __syncthreads();

    const int NR = K / MTK;   // 64 rounds
    for (int s = 0; s < NR - 1; ++s) {
        const int p = s & 1;
        AReg a = issueA(s + 1);        // global loads in flight during MFMAs
        BReg bnext = loadB(s + 1);
        compute_tile(p, bcur);
        commitA(1 - p, a);
        bcur = bnext;
        __syncthreads();
    }
    compute_tile((NR - 1) & 1, bcur);

    // epilogue: data-driven D mapping
    const int mwR = tm + mw;
    const int nwC = nb0 + nw;
    #pragma unroll
    for (int i = 0; i < 4; i++) {
        #pragma unroll
        for (int q = 0; q < 4; q++) {
            const int row = mwR + i * 16 + rloc + q * rstep;
            if (row < M) {
                double* Cr = C + (size_t)row * N + nwC + cloc + q * cstep;
                Cr[0]  = acc[i][0][q];
                Cr[16] = acc[i][1][q];
            }
        }
    }
}

// ---- GEMM (vector fallback = R7 verbatim, flag-gated) ----
__global__ __launch_bounds__(256, 3) void gemm_f64_sgpr(
    const float* __restrict__ A,
    const double* __restrict__ WdT,
    double* __restrict__ C, int M, int N, int K,
    const unsigned int* __restrict__ flag)
{
    {
        const unsigned int f = *flag;
        if (f - 1u <= 6u) return;   // MFMA path handled it
    }
    __shared__ double As[2][VTK][LDA];   // 16,640 B

    const int tid  = threadIdx.x;
    const int lane = tid & 63;
    const int nb = __builtin_amdgcn_readfirstlane(blockIdx.x * TN + (tid >> 6) * 16);
    const int tm = blockIdx.y * TM;

    const int kq = (tid & 1) * 4;   // 0 or 4
    const int r  = tid >> 1;        // 0..127

    double acc0[16], acc1[16];
    #pragma unroll
    for (int j = 0; j < 16; j++) { acc0[j] = 0.0; acc1[j] = 0.0; }

    const int ar = min(tm + r, M - 1);   // tail guard (loads only)
    const float* Ap = A + (size_t)ar * K + kq;

    {
        const float4 a0 = *(const float4*)(Ap);
        As[0][kq + 0][r] = (double)a0.x; As[0][kq + 1][r] = (double)a0.y;
        As[0][kq + 2][r] = (double)a0.z; As[0][kq + 3][r] = (double)a0.w;
    }
    __syncthreads();

    auto compute_tile = [&](int p, int k0) {
        #pragma unroll
        for (int kk = 0; kk < VTK; kk++) {
            const double* wr = WdT + (size_t)(k0 + kk) * N + nb;   // uniform
            const double2 a = *(const double2*)&As[p][kk][2 * lane];
            #pragma unroll
            for (int j = 0; j < 16; j++) {
                const double wj = wr[j];
                acc0[j] = fma(a.x, wj, acc0[j]);
                acc1[j] = fma(a.y, wj, acc1[j]);
            }
        }
    };

    const int NS = K / VTK;   // 128 tiles
    for (int s = 0; s < NS - 1; ++s) {
        const int p = s & 1;
        {
            const float4 a0 = *(const float4*)(Ap + (size_t)(s + 1) * VTK);
            const int q = 1 - p;
            As[q][kq + 0][r] = (double)a0.x; As[q][kq + 1][r] = (double)a0.y;
            As[q][kq + 2][r] = (double)a0.z; As[q][kq + 3][r] = (double)a0.w;
        }
        compute_tile(p, s * VTK);
        __syncthreads();
    }
    compute_tile((NS - 1) & 1, (NS - 1) * VTK);

    const int m0 = tm + 2 * lane;
    if (m0 < M) {
        double* Cr = C + (size_t)m0 * N + nb;
        #pragma unroll
        for (int j = 0; j < 8; j++)
            *(double2*)&Cr[2 * j] = double2{acc0[2 * j], acc0[2 * j + 1]};
    }
    if (m0 + 1 < M) {
        double* Cr = C + (size_t)(m0 + 1) * N + nb;
        #pragma unroll
        for (int j = 0; j < 8; j++)
            *(double2*)&Cr[2 * j] = double2{acc1[2 * j], acc1[2 * j + 1]};
    }
}

// ---- scan (unchanged, absmax-0.0 pedigree) ----
__global__ __launch_bounds__(256) void lif_scan_kernel(
    const double* __restrict__ Wx,
    const float* __restrict__ alpha,
    const float* __restrict__ u0,
    const float* __restrict__ s0,
    float* __restrict__ out,
    int b0, int T, int H)
{
    const int idx = blockIdx.x * blockDim.x + threadIdx.x;
    const int h  = idx & 1023;
    const int bl = idx >> 10;
    const int b  = b0 + bl;

    const double AMIN = 0.8187307530779818;   // exp(-1/5)
    const double AMAX = 0.9607894391523232;   // exp(-1/25)
    double a = (double)alpha[h];
    a = fmin(fmax(a, AMIN), AMAX);
    const double oma = 1.0 - a;

    double u = (double)u0[(size_t)b * H + h];
    double s = (double)s0[(size_t)b * H + h];

    const double* wp = Wx + (size_t)bl * T * H + h;
    float* op = out + (size_t)b * T * H + h;

    double v[8];
    #pragma unroll
    for (int p = 0; p < 8; p++) v[p] = wp[(size_t)p * H];

    for (int t0 = 0; t0 < T; t0 += 8) {
        double nv[8];
        const bool more = (t0 + 8) < T;
        const double* wn = wp + (size_t)(t0 + 8) * H;
        #pragma unroll
        for (int p = 0; p < 8; p++) nv[p] = more ? wn[(size_t)p * H] : 0.0;

        #pragma unroll
        for (int p = 0; p < 8; p++) {
            u = a * (u - s) + oma * v[p];           // exact ref op order
            s = (u - 1.0 > 0.0) ? 1.0 : 0.0;
            op[(size_t)(t0 + p) * H] = (float)s;
        }
        #pragma unroll
        for (int p = 0; p < 8; p++) v[p] = nv[p];
    }
}

extern "C" void kernel_launch(void* const* d_in, const int* in_sizes, int n_in,
                              void* d_out, int out_size, void* d_ws, size_t ws_size,
                              hipStream_t stream) {
    const float* x     = (const float*)d_in[0];   // [64,1000,1024]
    const float* W     = (const float*)d_in[1];   // [1024,1024]
    const float* alpha = (const float*)d_in[2];   // [1024]
    const float* u0    = (const float*)d_in[3];   // [64,1024]
    const float* s0    = (const float*)d_in[4];   // [64,1024]
    float* out = (float*)d_out;                   // [64,1000,1024] f32
    const int Bt = 64, T = 1000, I = 1024, H = 1024;

    // ws layout: [ WdT : 8 MiB f64 ][ wx : Bc*T*H f64 ] ... [ flag : 256 B tail ]
    double* wdT = (double*)d_ws;
    const size_t wdT_bytes = (size_t)I * H * sizeof(double);   // 8 MiB
    const size_t flag_off = (ws_size - 256) & ~(size_t)255;
    unsigned int* flag = (unsigned int*)((char*)d_ws + flag_off);
    double* wx = (double*)((char*)d_ws + wdT_bytes);
    const size_t avail = (flag_off > wdT_bytes) ? flag_off - wdT_bytes : 0;

    const size_t per_batch = (size_t)T * H * sizeof(double);   // 8.192 MB
    int Bc = 1;
    {
        const int cands[7] = {64, 32, 16, 8, 4, 2, 1};
        for (int c = 0; c < 7; c++) {
            if ((size_t)cands[c] * per_batch <= avail) { Bc = cands[c]; break; }
        }
    }

    transpose_w<<<dim3(1024 / 32, 1024 / 32), 256, 0, stream>>>(W, wdT);
    probe_mfma_layout<<<1, 64, 0, stream>>>(flag);

    for (int b0 = 0; b0 < Bt; b0 += Bc) {
        const int M = Bc * T;
        dim3 grid(H / TN, (M + TM - 1) / TM);
        gemm_f64_mfma<<<grid, 256, 0, stream>>>(
            x + (size_t)b0 * T * I, wdT, wx, M, H, I, flag);
        gemm_f64_sgpr<<<grid, 256, 0, stream>>>(
            x + (size_t)b0 * T * I, wdT, wx, M, H, I, flag);
        lif_scan_kernel<<<(Bc * H) / 256, 256, 0, stream>>>(
            wx, alpha, u0, s0, out, b0, T, H);
    }
}

// Round 6
// 2435.784 us; speedup vs baseline: 1.0271x; 1.0271x over previous
//
#include <hip/hip_runtime.h>

// LIF layer: Wx = x @ W^T (f64), then scan over T. B=64,T=1000,I=1024,H=1024.
// R13: merge of R10 (best measured: gemm 2255us, B staged in LDS) and R12
//     (occupancy 45%, but B-from-global exposed L2 latency -> 2346us).
//     Post-mortem R12: Bs bank conflicts were NOT on the critical path
//     (removing them changed nothing); the vmcnt drain before each round's
//     first MFMA (global B) was worse than R10's LDS read. So:
//       - B returns to LDS staging (R10 pattern, conflicts accepted).
//       - A tile stored in LDS as f32, cvt f64 at fragment read (exact ->
//         absmax-0.0 preserved). As 33.3->16.9KB; total LDS 33.8KB ->
//         4 blocks/CU = 16 waves/CU (R12's occupancy without its latency).
//     Probe + data-driven lane mapping + R7 vector fallback unchanged.

#define TM 128
#define TN 64
#define MTK 16     // MFMA kernel k-tile
#define VTK 8      // vector-fallback kernel k-tile (R7)
#define LDAF 132   // As row stride (floats): 132*4=528 B
#define LDA 130    // fallback As row stride (doubles)
#define LDB 66     // Bs row stride (doubles)

typedef double v4d __attribute__((ext_vector_type(4)));

// ---- pass 0: WdT[k][n] = (double)W[n][k] ----
__global__ __launch_bounds__(256) void transpose_w(
    const float* __restrict__ W, double* __restrict__ WdT)
{
    __shared__ float t[32][33];
    const int k0 = blockIdx.x * 32;
    const int n0 = blockIdx.y * 32;
    const int tx = threadIdx.x & 31;
    const int ty = threadIdx.x >> 5;   // 0..7
    #pragma unroll
    for (int i = 0; i < 4; i++)
        t[ty + 8 * i][tx] = W[(size_t)(n0 + ty + 8 * i) * 1024 + k0 + tx];
    __syncthreads();
    #pragma unroll
    for (int i = 0; i < 4; i++)
        WdT[(size_t)(k0 + ty + 8 * i) * 1024 + n0 + tx] = (double)t[tx][ty + 8 * i];
}

// ---- probe: discover v_mfma_f64_16x16x4f64 lane mappings on-device ----
// flag = imap*4 + dmap (imap 0/1, dmap 0..3), or 255 = none matched.
//   imap0: A[row=l&15][k=l>>4],  B[k=l>>4][col=l&15]
//   imap1: A[row=l>>2][k=l&3],   B[k=l&3][col=l>>2]
//   dmap0: d[q]=D[4*(l>>4)+q][l&15]     dmap1: d[q]=D[l&15][4*(l>>4)+q]
//   dmap2: d[q]=D[(l>>4)+4*q][l&15]     dmap3: d[q]=D[l&15][(l>>4)+4*q]
// Exact-integer asymmetric matrices -> bit-exact, transpose-detecting.
__global__ __launch_bounds__(64) void probe_mfma_layout(unsigned int* __restrict__ flag)
{
    __shared__ double Am[16][4];
    __shared__ double Bm[4][16];
    const int l = threadIdx.x;
    Am[l & 15][l >> 4] = (double)(1 + (l & 15) + 16 * (l >> 4));          // A[i][k]=1+i+16k
    Bm[l >> 4][l & 15] = 1.0 + 0.5 * (double)((l >> 4) + 4 * (l & 15));   // B[k][j]=1+.5(k+4j)
    __syncthreads();
    const v4d z = {0.0, 0.0, 0.0, 0.0};
    const double a0 = Am[l & 15][l >> 4];
    const double b0 = Bm[l >> 4][l & 15];
    const double a1 = Am[l >> 2][l & 3];
    const double b1 = Bm[l & 3][l >> 2];
    const v4d d0 = __builtin_amdgcn_mfma_f64_16x16x4f64(a0, b0, z, 0, 0, 0);
    const v4d d1 = __builtin_amdgcn_mfma_f64_16x16x4f64(a1, b1, z, 0, 0, 0);
    int ok[8];
    #pragma unroll
    for (int c = 0; c < 8; c++) ok[c] = 1;
    #pragma unroll
    for (int q = 0; q < 4; q++) {
        const int iD[4] = {4 * (l >> 4) + q, l & 15, (l >> 4) + 4 * q, l & 15};
        const int jD[4] = {l & 15, 4 * (l >> 4) + q, l & 15, (l >> 4) + 4 * q};
        #pragma unroll
        for (int dm = 0; dm < 4; dm++) {
            double ref = 0.0;
            #pragma unroll
            for (int k = 0; k < 4; k++) ref += Am[iD[dm]][k] * Bm[k][jD[dm]];
            if (d0[q] != ref) ok[dm] = 0;
            if (d1[q] != ref) ok[4 + dm] = 0;
        }
    }
    unsigned int f = 255u;
    for (int c = 7; c >= 0; --c)
        if (__all(ok[c])) f = (unsigned int)c;   // lowest passing wins
    if (l == 0) *flag = f;
}

// ---- GEMM (MFMA path): C[M,N] = A[M,K](f32) * WdT[K,N](f64) ----
// Runs only for flag in {1..7}. A staged in LDS as f32 (cvt at read);
// B staged in LDS as f64 (R10 pattern). One barrier per k-tile.
__global__ __launch_bounds__(256, 4) void gemm_f64_mfma(
    const float* __restrict__ A,
    const double* __restrict__ WdT,
    double* __restrict__ C, int M, int N, int K,
    const unsigned int* __restrict__ flag)
{
    const unsigned int f = *flag;
    if (f - 1u > 6u) return;            // only validated alternatives 1..7

    __shared__ float  As[2][MTK][LDAF]; // 16,896 B
    __shared__ double Bs[2][MTK][LDB];  // 16,896 B

    const int tid  = threadIdx.x;
    const int lane = tid & 63;
    const int l16  = lane & 15;
    const int kq4  = lane >> 4;
    const int wid  = tid >> 6;          // wave 0..3
    const int wr   = wid >> 1;          // wave row 0/1 (64 rows each)
    const int wc   = wid & 1;           // wave col 0/1 (32 cols each)

    const int imap = (int)(f >> 2);
    const int dmap = (int)(f & 3u);
    const int rowl = imap ? (lane >> 2) : l16;   // A-row / B-col within 16
    const int kl   = imap ? (lane & 3)  : kq4;   // k within the K=4 step
    int rloc, rstep, cloc, cstep;
    switch (dmap) {
        case 0:  rloc = 4 * kq4; rstep = 1; cloc = l16;     cstep = 0; break;
        case 1:  rloc = l16;     rstep = 0; cloc = 4 * kq4; cstep = 1; break;
        case 2:  rloc = kq4;     rstep = 4; cloc = l16;     cstep = 0; break;
        default: rloc = l16;     rstep = 0; cloc = kq4;     cstep = 4; break;
    }

    const int nb0 = blockIdx.x * TN;
    const int tm  = blockIdx.y * TM;

    // staging roles
    const int rA  = tid >> 1;           // A row 0..127
    const int kA  = (tid & 1) * 4;      // A k-quad base (0 or 4; +8 for 2nd)
    const int kkB = tid >> 4;           // B k row 0..15
    const int cBl = (tid & 15) * 4;     // B local col (4 doubles)

    v4d acc[4][2];
    #pragma unroll
    for (int i = 0; i < 4; i++)
        #pragma unroll
        for (int j = 0; j < 2; j++)
            acc[i][j] = (v4d)0.0;

    const int ar = min(tm + rA, M - 1);   // tail guard (loads only)
    const float* Apg = A + (size_t)ar * K;
    const double* Bpg = WdT + (size_t)kkB * N + nb0 + cBl;

    struct StReg { float4 a0, a1; double2 b0, b1; };
    auto issue = [&](int s) {
        StReg t;
        const int k0 = s * MTK;
        t.a0 = *(const float4*)(Apg + k0 + kA);
        t.a1 = *(const float4*)(Apg + k0 + kA + 8);
        const double* wp = Bpg + (size_t)k0 * N;
        t.b0 = *(const double2*)(wp);
        t.b1 = *(const double2*)(wp + 2);
        return t;
    };
    auto commit = [&](int buf, const StReg& t) {
        As[buf][kA + 0][rA] = t.a0.x;
        As[buf][kA + 1][rA] = t.a0.y;
        As[buf][kA + 2][rA] = t.a0.z;
        As[buf][kA + 3][rA] = t.a0.w;
        As[buf][kA + 8][rA] = t.a1.x;
        As[buf][kA + 9][rA] = t.a1.y;
        As[buf][kA + 10][rA] = t.a1.z;
        As[buf][kA + 11][rA] = t.a1.w;
        Bs[buf][kkB][cBl + 0] = t.b0.x;
        Bs[buf][kkB][cBl + 1] = t.b0.y;
        Bs[buf][kkB][cBl + 2] = t.b1.x;
        Bs[buf][kkB][cBl + 3] = t.b1.y;
    };

    const int mw = wr * 64;
    const int nw = wc * 32;
    auto compute_tile = [&](int p) {
        #pragma unroll
        for (int ks = 0; ks < 4; ++ks) {
            const int kk = ks * 4 + kl;
            double av[4], bv[2];
            #pragma unroll
            for (int i = 0; i < 4; i++)
                av[i] = (double)As[p][kk][mw + i * 16 + rowl];   // exact cvt
            #pragma unroll
            for (int j = 0; j < 2; j++) bv[j] = Bs[p][kk][nw + j * 16 + rowl];
            #pragma unroll
            for (int i = 0; i < 4; i++)
                #pragma unroll
                for (int j = 0; j < 2; j++)
                    acc[i][j] = __builtin_amdgcn_mfma_f64_16x16x4f64(
                        av[i], bv[j], acc[i][j], 0, 0, 0);
        }
    };

    // prologue: stage round 0 into buf 0
    commit(0, issue(0));
    __syncthreads();

    const int NR = K / MTK;   // 64 rounds
    for (int s = 0; s < NR - 1; ++s) {
        const int p = s & 1;
        StReg t = issue(s + 1);   // global loads in flight during MFMA block
        compute_tile(p);
        commit(1 - p, t);
        __syncthreads();
    }
    compute_tile((NR - 1) & 1);

    // epilogue: data-driven D mapping
    const int mwR = tm + mw;
    const int nwC = nb0 + nw;
    #pragma unroll
    for (int i = 0; i < 4; i++) {
        #pragma unroll
        for (int q = 0; q < 4; q++) {
            const int row = mwR + i * 16 + rloc + q * rstep;
            if (row < M) {
                double* Cr = C + (size_t)row * N + nwC + cloc + q * cstep;
                Cr[0]  = acc[i][0][q];
                Cr[16] = acc[i][1][q];
            }
        }
    }
}

// ---- GEMM (vector fallback = R7 verbatim, flag-gated) ----
__global__ __launch_bounds__(256, 3) void gemm_f64_sgpr(
    const float* __restrict__ A,
    const double* __restrict__ WdT,
    double* __restrict__ C, int M, int N, int K,
    const unsigned int* __restrict__ flag)
{
    {
        const unsigned int f = *flag;
        if (f - 1u <= 6u) return;   // MFMA path handled it
    }
    __shared__ double As[2][VTK][LDA];   // 16,640 B

    const int tid  = threadIdx.x;
    const int lane = tid & 63;
    const int nb = __builtin_amdgcn_readfirstlane(blockIdx.x * TN + (tid >> 6) * 16);
    const int tm = blockIdx.y * TM;

    const int kq = (tid & 1) * 4;   // 0 or 4
    const int r  = tid >> 1;        // 0..127

    double acc0[16], acc1[16];
    #pragma unroll
    for (int j = 0; j < 16; j++) { acc0[j] = 0.0; acc1[j] = 0.0; }

    const int ar = min(tm + r, M - 1);   // tail guard (loads only)
    const float* Ap = A + (size_t)ar * K + kq;

    {
        const float4 a0 = *(const float4*)(Ap);
        As[0][kq + 0][r] = (double)a0.x; As[0][kq + 1][r] = (double)a0.y;
        As[0][kq + 2][r] = (double)a0.z; As[0][kq + 3][r] = (double)a0.w;
    }
    __syncthreads();

    auto compute_tile = [&](int p, int k0) {
        #pragma unroll
        for (int kk = 0; kk < VTK; kk++) {
            const double* wr = WdT + (size_t)(k0 + kk) * N + nb;   // uniform
            const double2 a = *(const double2*)&As[p][kk][2 * lane];
            #pragma unroll
            for (int j = 0; j < 16; j++) {
                const double wj = wr[j];
                acc0[j] = fma(a.x, wj, acc0[j]);
                acc1[j] = fma(a.y, wj, acc1[j]);
            }
        }
    };

    const int NS = K / VTK;   // 128 tiles
    for (int s = 0; s < NS - 1; ++s) {
        const int p = s & 1;
        {
            const float4 a0 = *(const float4*)(Ap + (size_t)(s + 1) * VTK);
            const int q = 1 - p;
            As[q][kq + 0][r] = (double)a0.x; As[q][kq + 1][r] = (double)a0.y;
            As[q][kq + 2][r] = (double)a0.z; As[q][kq + 3][r] = (double)a0.w;
        }
        compute_tile(p, s * VTK);
        __syncthreads();
    }
    compute_tile((NS - 1) & 1, (NS - 1) * VTK);

    const int m0 = tm + 2 * lane;
    if (m0 < M) {
        double* Cr = C + (size_t)m0 * N + nb;
        #pragma unroll
        for (int j = 0; j < 8; j++)
            *(double2*)&Cr[2 * j] = double2{acc0[2 * j], acc0[2 * j + 1]};
    }
    if (m0 + 1 < M) {
        double* Cr = C + (size_t)(m0 + 1) * N + nb;
        #pragma unroll
        for (int j = 0; j < 8; j++)
            *(double2*)&Cr[2 * j] = double2{acc1[2 * j], acc1[2 * j + 1]};
    }
}

// ---- scan (unchanged, absmax-0.0 pedigree) ----
__global__ __launch_bounds__(256) void lif_scan_kernel(
    const double* __restrict__ Wx,
    const float* __restrict__ alpha,
    const float* __restrict__ u0,
    const float* __restrict__ s0,
    float* __restrict__ out,
    int b0, int T, int H)
{
    const int idx = blockIdx.x * blockDim.x + threadIdx.x;
    const int h  = idx & 1023;
    const int bl = idx >> 10;
    const int b  = b0 + bl;

    const double AMIN = 0.8187307530779818;   // exp(-1/5)
    const double AMAX = 0.9607894391523232;   // exp(-1/25)
    double a = (double)alpha[h];
    a = fmin(fmax(a, AMIN), AMAX);
    const double oma = 1.0 - a;

    double u = (double)u0[(size_t)b * H + h];
    double s = (double)s0[(size_t)b * H + h];

    const double* wp = Wx + (size_t)bl * T * H + h;
    float* op = out + (size_t)b * T * H + h;

    double v[8];
    #pragma unroll
    for (int p = 0; p < 8; p++) v[p] = wp[(size_t)p * H];

    for (int t0 = 0; t0 < T; t0 += 8) {
        double nv[8];
        const bool more = (t0 + 8) < T;
        const double* wn = wp + (size_t)(t0 + 8) * H;
        #pragma unroll
        for (int p = 0; p < 8; p++) nv[p] = more ? wn[(size_t)p * H] : 0.0;

        #pragma unroll
        for (int p = 0; p < 8; p++) {
            u = a * (u - s) + oma * v[p];           // exact ref op order
            s = (u - 1.0 > 0.0) ? 1.0 : 0.0;
            op[(size_t)(t0 + p) * H] = (float)s;
        }
        #pragma unroll
        for (int p = 0; p < 8; p++) v[p] = nv[p];
    }
}

extern "C" void kernel_launch(void* const* d_in, const int* in_sizes, int n_in,
                              void* d_out, int out_size, void* d_ws, size_t ws_size,
                              hipStream_t stream) {
    const float* x     = (const float*)d_in[0];   // [64,1000,1024]
    const float* W     = (const float*)d_in[1];   // [1024,1024]
    const float* alpha = (const float*)d_in[2];   // [1024]
    const float* u0    = (const float*)d_in[3];   // [64,1024]
    const float* s0    = (const float*)d_in[4];   // [64,1024]
    float* out = (float*)d_out;                   // [64,1000,1024] f32
    const int Bt = 64, T = 1000, I = 1024, H = 1024;

    // ws layout: [ WdT : 8 MiB f64 ][ wx : Bc*T*H f64 ] ... [ flag : 256 B tail ]
    double* wdT = (double*)d_ws;
    const size_t wdT_bytes = (size_t)I * H * sizeof(double);   // 8 MiB
    const size_t flag_off = (ws_size - 256) & ~(size_t)255;
    unsigned int* flag = (unsigned int*)((char*)d_ws + flag_off);
    double* wx = (double*)((char*)d_ws + wdT_bytes);
    const size_t avail = (flag_off > wdT_bytes) ? flag_off - wdT_bytes : 0;

    const size_t per_batch = (size_t)T * H * sizeof(double);   // 8.192 MB
    int Bc = 1;
    {
        const int cands[7] = {64, 32, 16, 8, 4, 2, 1};
        for (int c = 0; c < 7; c++) {
            if ((size_t)cands[c] * per_batch <= avail) { Bc = cands[c]; break; }
        }
    }

    transpose_w<<<dim3(1024 / 32, 1024 / 32), 256, 0, stream>>>(W, wdT);
    probe_mfma_layout<<<1, 64, 0, stream>>>(flag);

    for (int b0 = 0; b0 < Bt; b0 += Bc) {
        const int M = Bc * T;
        dim3 grid(H / TN, (M + TM - 1) / TM);
        gemm_f64_mfma<<<grid, 256, 0, stream>>>(
            x + (size_t)b0 * T * I, wdT, wx, M, H, I, flag);
        gemm_f64_sgpr<<<grid, 256, 0, stream>>>(
            x + (size_t)b0 * T * I, wdT, wx, M, H, I, flag);
        lif_scan_kernel<<<(Bc * H) / 256, 256, 0, stream>>>(
            wx, alpha, u0, s0, out, b0, T, H);
    }
}